// Round 16
// baseline (314.134 us; speedup 1.0000x reference)
//
#include <hip/hip_runtime.h>
#include <math.h>

#define N_NODES 50000
#define N_EDGES 800000
#define N_GRAPHS 512
#define CAP 62      // u16 slots per 128B bucket record; max degree (Poisson 16) ~45
#define NBINS 196   // bin = dst>>8 ; 196 bins of 256 nodes
#define CAPB 5120   // bin list capacity (expected ~4082, sigma ~64)
#define ABLK 4096   // edges per binning block (16/thread)
#define PROP_BLOCKS 2048
#define PROP_WAVES (PROP_BLOCKS * 4)
#define POOL_BLOCKS 512
#define P64_BLOCKS (PROP_BLOCKS - POOL_BLOCKS)  // 1536 prop blocks in fused kernel

typedef unsigned short u16;
typedef unsigned int u32;
typedef __attribute__((ext_vector_type(8))) short bf16x8_t;
typedef __attribute__((ext_vector_type(4))) float f32x4_t;
typedef __attribute__((ext_vector_type(4))) unsigned int u32x4_t;

constexpr int NBLK_A = (N_EDGES + ABLK - 1) / ABLK;  // 196
constexpr int WCONV_TOT = 49152;
constexpr int NCW = (WCONV_TOT + 255) / 256;         // 192

// ---- bf16 helpers (RTNE, finite values only) ----
__device__ __forceinline__ u16 f2bf(float f) {
    u32 u = __builtin_bit_cast(u32, f);
    return (u16)((u + 0x7fffu + ((u >> 16) & 1u)) >> 16);
}
__device__ __forceinline__ float bf2f(u16 s) {
    return __builtin_bit_cast(float, (u32)s << 16);
}
__device__ __forceinline__ float bf_lo(u32 u) { return __builtin_bit_cast(float, u << 16); }
__device__ __forceinline__ float bf_hi(u32 u) { return __builtin_bit_cast(float, u & 0xffff0000u); }

__device__ __forceinline__ bf16x8_t cvt8(const float* p) {
    float4 a = *reinterpret_cast<const float4*>(p);
    float4 b = *reinterpret_cast<const float4*>(p + 4);
    u32x4_t w;
    w.x = (u32)f2bf(a.x) | ((u32)f2bf(a.y) << 16);
    w.y = (u32)f2bf(a.z) | ((u32)f2bf(a.w) << 16);
    w.z = (u32)f2bf(b.x) | ((u32)f2bf(b.y) << 16);
    w.w = (u32)f2bf(b.z) | ((u32)f2bf(b.w) << 16);
    return __builtin_bit_cast(bf16x8_t, w);
}

// ---------------- block-wide exclusive scan helper (256 threads) ----------------
__device__ __forceinline__ int block_exscan(int val, int* lds, int tid) {
    lds[tid] = val;
    __syncthreads();
#pragma unroll
    for (int off = 1; off < 256; off <<= 1) {
        int t = (tid >= off) ? lds[tid - off] : 0;
        __syncthreads();
        lds[tid] += t;
        __syncthreads();
    }
    return lds[tid] - val;
}

// ---------------- pass 1: bin edges by dst>>8 (16 edges/thread) + convert_wT tail ----------
__global__ __launch_bounds__(256) void pre_scatter(const int* __restrict__ src,
                                                   const int* __restrict__ dst,
                                                   u32* __restrict__ binCnt,
                                                   u32* __restrict__ binList,
                                                   const float* __restrict__ W1, u16* __restrict__ wt1,
                                                   const float* __restrict__ W2, u16* __restrict__ wt2,
                                                   const float* __restrict__ W3, u16* __restrict__ wt3,
                                                   const float* __restrict__ W4, u16* __restrict__ wt4) {
    __shared__ int cur[256];
    __shared__ int lsStart[256];
    __shared__ int gbase[256];
    __shared__ int scanbuf[256];
    __shared__ u32 stage[ABLK];
    __shared__ int gpos[ABLK];
    int t = threadIdx.x;
    if (blockIdx.x >= NBLK_A) {
        int idx = (blockIdx.x - NBLK_A) * 256 + t;
        if (idx < WCONV_TOT) {
            const float* Wf;
            u16* Wt;
            int K, N, off;
            if (idx < 16384)      { Wf = W1; Wt = wt1; K = 128; N = 128; off = 0; }
            else if (idx < 24576) { Wf = W2; Wt = wt2; K = 128; N = 64;  off = 16384; }
            else if (idx < 32768) { Wf = W3; Wt = wt3; K = 64;  N = 128; off = 24576; }
            else                  { Wf = W4; Wt = wt4; K = 128; N = 128; off = 32768; }
            int q = idx - off;
            int k = q / N, n = q % N;
            Wt[n * K + k] = f2bf(Wf[q]);
        }
        return;
    }
    int e0 = blockIdx.x * ABLK;
    int nEdge = min(ABLK, N_EDGES - e0);  // 4096, or 1280 in last block (multiple of 4)

    cur[t] = 0;
    __syncthreads();

    int myBin[16], myRank[16];
    u32 myPack[16];
#pragma unroll
    for (int p = 0; p < 4; p++) {
        int off = p * 1024 + t * 4;
        bool ok = off < nEdge;
        int4 dv = ok ? *reinterpret_cast<const int4*>(dst + e0 + off) : make_int4(0, 0, 0, 0);
        int4 sv = ok ? *reinterpret_cast<const int4*>(src + e0 + off) : make_int4(0, 0, 0, 0);
        int ds[4] = {dv.x, dv.y, dv.z, dv.w};
        int ss[4] = {sv.x, sv.y, sv.z, sv.w};
#pragma unroll
        for (int j = 0; j < 4; j++) {
            int q = p * 4 + j;
            myBin[q] = ok ? (ds[j] >> 8) : -1;
            myPack[q] = (u32)(ss[j] & 0xFFFF) | ((u32)(ds[j] & 0xFF) << 16);
            myRank[q] = ok ? atomicAdd(&cur[ds[j] >> 8], 1) : 0;
        }
    }
    __syncthreads();
    int v = cur[t];
    int ex = block_exscan(v, scanbuf, t);
    lsStart[t] = ex;
    gbase[t] = (v > 0) ? (int)atomicAdd(&binCnt[t * 16], (u32)v) : 0;
    __syncthreads();
#pragma unroll
    for (int q = 0; q < 16; q++) {
        if (myBin[q] >= 0) {
            int idx = lsStart[myBin[q]] + myRank[q];
            int pq = gbase[myBin[q]] + myRank[q];
            stage[idx] = myPack[q];
            gpos[idx] = (pq < CAPB) ? (myBin[q] * CAPB + pq) : -1;
        }
    }
    __syncthreads();
    for (int i = t; i < nEdge; i += 256) {
        int pq = gpos[i];
        if (pq >= 0) binList[pq] = stage[i];
    }
}

// ---------------- pass 2: build 256-node bucket slice in LDS (stride-33 padded) -------
__global__ __launch_bounds__(256) void bucket_build(const u32* __restrict__ binList,
                                                    const u32* __restrict__ binCnt,
                                                    u32* __restrict__ bucket,
                                                    float* __restrict__ dis) {
    __shared__ u32 rec[256 * 33];  // 33.8 KB
    int b = blockIdx.x, t = threadIdx.x;
    for (int i = t; i < 256 * 33; i += 256) rec[i] = 0;
    __syncthreads();
    int ecnt = min((int)binCnt[b * 16], CAPB);
    const u32* lst = binList + (size_t)b * CAPB;
    u16* rec16 = reinterpret_cast<u16*>(rec);
    for (int i = t; i < ecnt; i += 256) {
        u32 pk = lst[i];
        int dlow = (pk >> 16) & 0xFF;
        int pos = (int)atomicAdd(&rec[dlow * 33], 1u);
        if (pos < CAP) rec16[dlow * 66 + 2 + pos] = (u16)(pk & 0xFFFF);
    }
    __syncthreads();
    int node0 = b * 256;
    int nNode = min(256, N_NODES - node0);
    for (int i = t; i < nNode * 32; i += 256)
        bucket[(size_t)node0 * 32 + i] = rec[(i >> 5) * 33 + (i & 31)];
    if (t < nNode) dis[node0 + t] = 1.0f / sqrtf((float)rec[t * 33] + 1.0f);
}

// ---------------- bf16 MFMA GEMM: C[M,N] = A[M,K] @ Wt[N,K]^T (+bias, relu, row-scale) --------
template <int N, int K, bool BIAS, bool RELU, bool SCALE, bool AF32>
__global__ __launch_bounds__(256) void gemm_mfma(const void* __restrict__ Avp,
                                                 const u16* __restrict__ Wt,
                                                 const float* __restrict__ bias,
                                                 const float* __restrict__ dis,
                                                 u16* __restrict__ C) {
    constexpr int KB = K / 32;
    constexpr int TN = N / 64;
    constexpr int TM = (N_NODES + 63) / 64;  // 782
    int wave = threadIdx.x >> 6;
    int lane = threadIdx.x & 63;
    int W = blockIdx.x * 4 + wave;
    if (W >= TM * TN) return;
    int tm = W / TN, tn = W % TN;
    int r16 = lane & 15;
    int kg = lane >> 4;

    bf16x8_t bf[4][KB];
#pragma unroll
    for (int nr = 0; nr < 4; nr++) {
        int colg = tn * 64 + nr * 16 + r16;
#pragma unroll
        for (int kb = 0; kb < KB; kb++)
            bf[nr][kb] = *reinterpret_cast<const bf16x8_t*>(Wt + (size_t)colg * K + kb * 32 + kg * 8);
    }

    f32x4_t acc[4][4];
#pragma unroll
    for (int mr = 0; mr < 4; mr++)
#pragma unroll
        for (int nr = 0; nr < 4; nr++)
#pragma unroll
            for (int t = 0; t < 4; t++) acc[mr][nr][t] = 0.f;

#pragma unroll
    for (int mr = 0; mr < 4; mr++) {
        int row = tm * 64 + mr * 16 + r16;
        if (row >= N_NODES) row = N_NODES - 1;
        bf16x8_t af[KB];
#pragma unroll
        for (int kb = 0; kb < KB; kb++) {
            if constexpr (AF32) {
                af[kb] = cvt8((const float*)Avp + (size_t)row * K + kb * 32 + kg * 8);
            } else {
                af[kb] = *reinterpret_cast<const bf16x8_t*>((const u16*)Avp + (size_t)row * K + kb * 32 + kg * 8);
            }
        }
#pragma unroll
        for (int kb = 0; kb < KB; kb++)
#pragma unroll
            for (int nr = 0; nr < 4; nr++)
                acc[mr][nr] = __builtin_amdgcn_mfma_f32_16x16x32_bf16(af[kb], bf[nr][kb],
                                                                      acc[mr][nr], 0, 0, 0);
    }

#pragma unroll
    for (int mr = 0; mr < 4; mr++) {
        float sc[4];
#pragma unroll
        for (int r = 0; r < 4; r++) {
            int row = tm * 64 + mr * 16 + kg * 4 + r;
            sc[r] = (SCALE && row < N_NODES) ? dis[row] : 1.f;
        }
#pragma unroll
        for (int nr = 0; nr < 4; nr++) {
            int colg = tn * 64 + nr * 16 + r16;
            float bv = BIAS ? bias[colg] : 0.f;
#pragma unroll
            for (int r = 0; r < 4; r++) {
                int row = tm * 64 + mr * 16 + kg * 4 + r;
                if (row < N_NODES) {
                    float v = acc[mr][nr][r] + bv;
                    if (RELU) v = fmaxf(v, 0.f);
                    if (SCALE) v *= sc[r];
                    C[(size_t)row * N + colg] = f2bf(v);
                }
            }
        }
    }
}

// ---------------- fused 2-layer MLP: out = dis ⊙ (relu(t·W3 + b3) · W4) ----------------
__global__ __launch_bounds__(256) void mlp2(const u16* __restrict__ t_in,   // [N_NODES][64]
                                            const u16* __restrict__ wt3,    // [128][64]
                                            const float* __restrict__ b3,
                                            const u16* __restrict__ wt4,    // [128][128]
                                            const float* __restrict__ dis,
                                            u16* __restrict__ out) {        // [N_NODES][128]
    __shared__ u16 h2s[64 * 128];  // 16 KB; byte addr swizzle: off ^= (row&7)<<4
    char* h2b = reinterpret_cast<char*>(h2s);
    int wv = threadIdx.x >> 6;
    int lane = threadIdx.x & 63;
    int r16 = lane & 15;
    int kg = lane >> 4;
    int row0 = blockIdx.x * 64;

    // ---- phase A: h2 cols [wv*32, wv*32+32) = relu(t_tile x W3 + b3) ----
    {
        bf16x8_t bf[2][2];
#pragma unroll
        for (int nr = 0; nr < 2; nr++) {
            int colg = wv * 32 + nr * 16 + r16;
#pragma unroll
            for (int kb = 0; kb < 2; kb++)
                bf[nr][kb] = *reinterpret_cast<const bf16x8_t*>(wt3 + (size_t)colg * 64 + kb * 32 + kg * 8);
        }
        f32x4_t acc[4][2];
#pragma unroll
        for (int mr = 0; mr < 4; mr++)
#pragma unroll
            for (int nr = 0; nr < 2; nr++)
#pragma unroll
                for (int q = 0; q < 4; q++) acc[mr][nr][q] = 0.f;
#pragma unroll
        for (int mr = 0; mr < 4; mr++) {
            int row = row0 + mr * 16 + r16;
            if (row >= N_NODES) row = N_NODES - 1;
            bf16x8_t af[2];
#pragma unroll
            for (int kb = 0; kb < 2; kb++)
                af[kb] = *reinterpret_cast<const bf16x8_t*>(t_in + (size_t)row * 64 + kb * 32 + kg * 8);
#pragma unroll
            for (int kb = 0; kb < 2; kb++)
#pragma unroll
                for (int nr = 0; nr < 2; nr++)
                    acc[mr][nr] = __builtin_amdgcn_mfma_f32_16x16x32_bf16(af[kb], bf[nr][kb],
                                                                          acc[mr][nr], 0, 0, 0);
        }
#pragma unroll
        for (int mr = 0; mr < 4; mr++) {
#pragma unroll
            for (int nr = 0; nr < 2; nr++) {
                int colg = wv * 32 + nr * 16 + r16;
                float bv = b3[colg];
#pragma unroll
                for (int r = 0; r < 4; r++) {
                    int rowl = mr * 16 + kg * 4 + r;
                    float v = fmaxf(acc[mr][nr][r] + bv, 0.f);
                    int off = rowl * 256 + colg * 2;
                    *reinterpret_cast<u16*>(h2b + (off ^ ((rowl & 7) << 4))) = f2bf(v);
                }
            }
        }
    }
    __syncthreads();

    // ---- phase B: out cols [wv*32, wv*32+32) = dis ⊙ (h2 x W4) ----
    {
        bf16x8_t bf[2][4];
#pragma unroll
        for (int nr = 0; nr < 2; nr++) {
            int colg = wv * 32 + nr * 16 + r16;
#pragma unroll
            for (int kb = 0; kb < 4; kb++)
                bf[nr][kb] = *reinterpret_cast<const bf16x8_t*>(wt4 + (size_t)colg * 128 + kb * 32 + kg * 8);
        }
        f32x4_t acc[4][2];
#pragma unroll
        for (int mr = 0; mr < 4; mr++)
#pragma unroll
            for (int nr = 0; nr < 2; nr++)
#pragma unroll
                for (int q = 0; q < 4; q++) acc[mr][nr][q] = 0.f;
#pragma unroll
        for (int mr = 0; mr < 4; mr++) {
            int rowl = mr * 16 + r16;
            bf16x8_t af[4];
#pragma unroll
            for (int kb = 0; kb < 4; kb++) {
                int off = rowl * 256 + kb * 64 + kg * 16;
                af[kb] = *reinterpret_cast<const bf16x8_t*>(h2b + (off ^ ((rowl & 7) << 4)));
            }
#pragma unroll
            for (int kb = 0; kb < 4; kb++)
#pragma unroll
                for (int nr = 0; nr < 2; nr++)
                    acc[mr][nr] = __builtin_amdgcn_mfma_f32_16x16x32_bf16(af[kb], bf[nr][kb],
                                                                          acc[mr][nr], 0, 0, 0);
        }
#pragma unroll
        for (int mr = 0; mr < 4; mr++) {
            float sc[4];
#pragma unroll
            for (int r = 0; r < 4; r++) {
                int row = row0 + mr * 16 + kg * 4 + r;
                sc[r] = (row < N_NODES) ? dis[row] : 1.f;
            }
#pragma unroll
            for (int nr = 0; nr < 2; nr++) {
                int colg = wv * 32 + nr * 16 + r16;
#pragma unroll
                for (int r = 0; r < 4; r++) {
                    int row = row0 + mr * 16 + kg * 4 + r;
                    if (row < N_NODES)
                        out[(size_t)row * 128 + colg] = f2bf(acc[mr][nr][r] * sc[r]);
                }
            }
        }
    }
}

// ---------------- propagate body over pre-scaled rows h' = dis ⊙ h ----------------
template <int F, bool RELU, bool BIAS, bool WF32, bool WBF16, bool SCALEOUT>
__device__ void prop_dev(const u16* __restrict__ h, const u32* __restrict__ bucket,
                         const float* __restrict__ dis, const float* __restrict__ bias,
                         float* __restrict__ out_f, u16* __restrict__ out_b,
                         int wid, int nwaves, int lane) {
    float2 bv2 = make_float2(0.f, 0.f);
    float bv1 = 0.f;
    if (BIAS) {
        if (F == 128) bv2 = reinterpret_cast<const float2*>(bias)[lane];
        else          bv1 = bias[lane];
    }
    for (int w = wid; w < N_NODES; w += nwaves) {
        const u32* bw = bucket + (size_t)w * 32;
        int deg = __builtin_amdgcn_readfirstlane(min((int)bw[0], CAP));
        const u16* slots = reinterpret_cast<const u16*>(bw) + 2;
        const u32* sw = reinterpret_cast<const u32*>(reinterpret_cast<const char*>(bw) + 4);
        float di = dis[w];

        if (F == 128) {
            const u32* hw = reinterpret_cast<const u32*>(h);  // 64 u32 per row
            float2 a0 = {0.f, 0.f}, a1 = {0.f, 0.f}, a2 = {0.f, 0.f}, a3 = {0.f, 0.f};
            int i = 0;
            for (; i + 16 <= deg; i += 16) {
                u32 cw[8], hv[16];
#pragma unroll
                for (int j = 0; j < 8; j++) cw[j] = sw[(i >> 1) + j];
#pragma unroll
                for (int j = 0; j < 8; j++) {
                    hv[2 * j]     = hw[(size_t)(cw[j] & 0xffffu) * 64 + lane];
                    hv[2 * j + 1] = hw[(size_t)(cw[j] >> 16) * 64 + lane];
                }
#pragma unroll
                for (int j = 0; j < 16; j++) {
                    float lo = bf_lo(hv[j]), hi = bf_hi(hv[j]);
                    if ((j & 3) == 0) { a0.x += lo; a0.y += hi; }
                    else if ((j & 3) == 1) { a1.x += lo; a1.y += hi; }
                    else if ((j & 3) == 2) { a2.x += lo; a2.y += hi; }
                    else { a3.x += lo; a3.y += hi; }
                }
            }
            for (; i + 8 <= deg; i += 8) {
                u32 cw[4], hv[8];
#pragma unroll
                for (int j = 0; j < 4; j++) cw[j] = sw[(i >> 1) + j];
#pragma unroll
                for (int j = 0; j < 4; j++) {
                    hv[2 * j]     = hw[(size_t)(cw[j] & 0xffffu) * 64 + lane];
                    hv[2 * j + 1] = hw[(size_t)(cw[j] >> 16) * 64 + lane];
                }
#pragma unroll
                for (int j = 0; j < 8; j++) {
                    float lo = bf_lo(hv[j]), hi = bf_hi(hv[j]);
                    if ((j & 3) == 0) { a0.x += lo; a0.y += hi; }
                    else if ((j & 3) == 1) { a1.x += lo; a1.y += hi; }
                    else if ((j & 3) == 2) { a2.x += lo; a2.y += hi; }
                    else { a3.x += lo; a3.y += hi; }
                }
            }
            for (; i < deg; i++) {
                u32 u = hw[(size_t)slots[i] * 64 + lane];
                a0.x += bf_lo(u);
                a0.y += bf_hi(u);
            }
            u32 su = hw[(size_t)w * 64 + lane];
            float ox = (a0.x + a1.x + a2.x + a3.x + bf_lo(su)) * di;
            float oy = (a0.y + a1.y + a2.y + a3.y + bf_hi(su)) * di;
            if (BIAS) { ox += bv2.x; oy += bv2.y; }
            if (RELU) { ox = fmaxf(ox, 0.f); oy = fmaxf(oy, 0.f); }
            if (WF32) {
                reinterpret_cast<float2*>(out_f + (size_t)w * 128)[lane] = make_float2(ox, oy);
            }
            if (WBF16) {
                float wx = SCALEOUT ? ox * di : ox;
                float wy = SCALEOUT ? oy * di : oy;
                u32 pk = (u32)f2bf(wx) | ((u32)f2bf(wy) << 16);
                reinterpret_cast<u32*>(out_b)[(size_t)w * 64 + lane] = pk;
            }
        } else {
            float a0 = 0.f, a1 = 0.f, a2 = 0.f, a3 = 0.f;
            int i = 0;
            for (; i + 16 <= deg; i += 16) {
                u32 cw[8];
                u16 hv[16];
#pragma unroll
                for (int j = 0; j < 8; j++) cw[j] = sw[(i >> 1) + j];
#pragma unroll
                for (int j = 0; j < 8; j++) {
                    hv[2 * j]     = h[(size_t)(cw[j] & 0xffffu) * 64 + lane];
                    hv[2 * j + 1] = h[(size_t)(cw[j] >> 16) * 64 + lane];
                }
#pragma unroll
                for (int j = 0; j < 16; j++) {
                    float v = bf2f(hv[j]);
                    if ((j & 3) == 0) a0 += v;
                    else if ((j & 3) == 1) a1 += v;
                    else if ((j & 3) == 2) a2 += v;
                    else a3 += v;
                }
            }
            for (; i + 8 <= deg; i += 8) {
                u32 cw[4];
                u16 hv[8];
#pragma unroll
                for (int j = 0; j < 4; j++) cw[j] = sw[(i >> 1) + j];
#pragma unroll
                for (int j = 0; j < 4; j++) {
                    hv[2 * j]     = h[(size_t)(cw[j] & 0xffffu) * 64 + lane];
                    hv[2 * j + 1] = h[(size_t)(cw[j] >> 16) * 64 + lane];
                }
#pragma unroll
                for (int j = 0; j < 8; j++) {
                    float v = bf2f(hv[j]);
                    if ((j & 3) == 0) a0 += v;
                    else if ((j & 3) == 1) a1 += v;
                    else if ((j & 3) == 2) a2 += v;
                    else a3 += v;
                }
            }
            for (; i < deg; i++) a0 += bf2f(h[(size_t)slots[i] * 64 + lane]);
            float o = (a0 + a1 + a2 + a3 + bf2f(h[(size_t)w * 64 + lane])) * di;
            if (BIAS) o += bv1;
            if (RELU) o = fmaxf(o, 0.f);
            if (WF32) out_f[(size_t)w * 64 + lane] = o;
            if (WBF16) out_b[(size_t)w * 64 + lane] = f2bf(SCALEOUT ? o * di : o);
        }
    }
}

template <int F, bool RELU, bool BIAS, bool WF32, bool WBF16, bool SCALEOUT>
__global__ __launch_bounds__(256) void propagate_k(const u16* __restrict__ h,
                                                   const u32* __restrict__ bucket,
                                                   const float* __restrict__ dis,
                                                   const float* __restrict__ bias,
                                                   float* __restrict__ out_f,
                                                   u16* __restrict__ out_b) {
    prop_dev<F, RELU, BIAS, WF32, WBF16, SCALEOUT>(h, bucket, dis, bias, out_f, out_b,
        (int)(blockIdx.x * 4 + (threadIdx.x >> 6)), PROP_WAVES, threadIdx.x & 63);
}

// ---------------- fused L1 propagate + GEMM-L2 matvec ----------------
// prop(F=128, relu, bias b1) yields h1 in-wave: ox = col 2*lane, oy = col 2*lane+1
// (u32 word `lane` of the bf16 row holds elements 2*lane, 2*lane+1).
// Matvec: c1[w][j] = dis[w] * Σ_k h1[k]·W2[k][j];
//   h1[2kk]   = ox of lane kk,  h1[2kk+1] = oy of lane kk,
//   W2s[kk*64+j] = pack(W2[2kk][j], W2[2kk+1][j]).
__global__ __launch_bounds__(256) void prop128_gemm64(const u16* __restrict__ h,
                                                      const u32* __restrict__ bucket,
                                                      const float* __restrict__ dis,
                                                      const float* __restrict__ b1,
                                                      const u16* __restrict__ wt2,  // [64][128]
                                                      u16* __restrict__ c1out) {
    __shared__ u32 W2s[64 * 64];  // 16 KB
    const u32* wt2u = reinterpret_cast<const u32*>(wt2);
    int t = threadIdx.x;
    for (int i = t; i < 4096; i += 256) {
        int j = i >> 6, kk = i & 63;
        W2s[kk * 64 + j] = wt2u[j * 64 + kk];  // transpose: matvec reads lane-consecutive
    }
    __syncthreads();
    int wid = (int)(blockIdx.x * 4 + (t >> 6));
    int lane = t & 63;
    float2 bv2 = reinterpret_cast<const float2*>(b1)[lane];
    const u32* hw = reinterpret_cast<const u32*>(h);

    for (int w = wid; w < N_NODES; w += PROP_WAVES) {
        const u32* bw = bucket + (size_t)w * 32;
        int deg = __builtin_amdgcn_readfirstlane(min((int)bw[0], CAP));
        const u16* slots = reinterpret_cast<const u16*>(bw) + 2;
        const u32* sw = reinterpret_cast<const u32*>(reinterpret_cast<const char*>(bw) + 4);
        float di = dis[w];

        float2 a0 = {0.f, 0.f}, a1 = {0.f, 0.f}, a2 = {0.f, 0.f}, a3 = {0.f, 0.f};
        int i = 0;
        for (; i + 16 <= deg; i += 16) {
            u32 cw[8], hv[16];
#pragma unroll
            for (int j = 0; j < 8; j++) cw[j] = sw[(i >> 1) + j];
#pragma unroll
            for (int j = 0; j < 8; j++) {
                hv[2 * j]     = hw[(size_t)(cw[j] & 0xffffu) * 64 + lane];
                hv[2 * j + 1] = hw[(size_t)(cw[j] >> 16) * 64 + lane];
            }
#pragma unroll
            for (int j = 0; j < 16; j++) {
                float lo = bf_lo(hv[j]), hi = bf_hi(hv[j]);
                if ((j & 3) == 0) { a0.x += lo; a0.y += hi; }
                else if ((j & 3) == 1) { a1.x += lo; a1.y += hi; }
                else if ((j & 3) == 2) { a2.x += lo; a2.y += hi; }
                else { a3.x += lo; a3.y += hi; }
            }
        }
        for (; i + 8 <= deg; i += 8) {
            u32 cw[4], hv[8];
#pragma unroll
            for (int j = 0; j < 4; j++) cw[j] = sw[(i >> 1) + j];
#pragma unroll
            for (int j = 0; j < 4; j++) {
                hv[2 * j]     = hw[(size_t)(cw[j] & 0xffffu) * 64 + lane];
                hv[2 * j + 1] = hw[(size_t)(cw[j] >> 16) * 64 + lane];
            }
#pragma unroll
            for (int j = 0; j < 8; j++) {
                float lo = bf_lo(hv[j]), hi = bf_hi(hv[j]);
                if ((j & 3) == 0) { a0.x += lo; a0.y += hi; }
                else if ((j & 3) == 1) { a1.x += lo; a1.y += hi; }
                else if ((j & 3) == 2) { a2.x += lo; a2.y += hi; }
                else { a3.x += lo; a3.y += hi; }
            }
        }
        for (; i < deg; i++) {
            u32 u = hw[(size_t)slots[i] * 64 + lane];
            a0.x += bf_lo(u);
            a0.y += bf_hi(u);
        }
        u32 su = hw[(size_t)w * 64 + lane];
        float ox = fmaxf((a0.x + a1.x + a2.x + a3.x + bf_lo(su)) * di + bv2.x, 0.f);
        float oy = fmaxf((a0.y + a1.y + a2.y + a3.y + bf_hi(su)) * di + bv2.y, 0.f);

        // matvec over interleaved layout: h1[2kk]=shfl(ox,kk), h1[2kk+1]=shfl(oy,kk)
        float acc = 0.f;
#pragma unroll
        for (int kk = 0; kk < 64; kk++) {
            float ha = __shfl(ox, kk);
            float hb = __shfl(oy, kk);
            u32 wp = W2s[kk * 64 + lane];
            acc = fmaf(ha, bf_lo(wp), acc);
            acc = fmaf(hb, bf_hi(wp), acc);
        }
        c1out[(size_t)w * 64 + lane] = f2bf(di * acc);
    }
}

// ---------------- L3 propagate + pooling fused (role split by blockIdx) ----------------
__global__ __launch_bounds__(256) void prop64_pool(const u16* __restrict__ h,
                                                   const u32* __restrict__ bucket,
                                                   const float* __restrict__ dis,
                                                   u16* __restrict__ out_b,
                                                   const float* __restrict__ z,
                                                   const int* __restrict__ batch,
                                                   float* __restrict__ agg) {
    int wave = threadIdx.x >> 6;
    int lane = threadIdx.x & 63;
    if (blockIdx.x >= P64_BLOCKS) {
        __shared__ float part[3][64];
        int g = blockIdx.x - P64_BLOCKS;  // one graph per block
        int l = 0, hh = N_NODES;
        while (l < hh) { int m = (l + hh) >> 1; if (batch[m] < g) l = m + 1; else hh = m; }
        int s = l;
        hh = N_NODES;
        while (l < hh) { int m = (l + hh) >> 1; if (batch[m] < g + 1) l = m + 1; else hh = m; }
        int e = l;
        float acc[4] = {0.f, 0.f, 0.f, 0.f};
        int i = s + wave;
        for (; i + 28 < e; i += 32) {  // 8 independent loads in flight
            float v[8];
#pragma unroll
            for (int j = 0; j < 8; j++) v[j] = z[(size_t)(i + j * 4) * 64 + lane];
#pragma unroll
            for (int j = 0; j < 8; j++) acc[j & 3] += v[j];
        }
        for (; i < e; i += 4) acc[0] += z[(size_t)i * 64 + lane];
        float a = acc[0] + acc[1] + acc[2] + acc[3];
        if (wave) part[wave - 1][lane] = a;
        __syncthreads();
        if (wave == 0) {
            a += part[0][lane] + part[1][lane] + part[2][lane];
            agg[(size_t)g * 64 + lane] = a / fmaxf((float)(e - s), 1.0f);
        }
        return;
    }
    prop_dev<64, false, false, false, true, false>(h, bucket, dis, nullptr, nullptr, out_b,
        (int)(blockIdx.x * 4 + wave), P64_BLOCKS * 4, lane);
}

extern "C" void kernel_launch(void* const* d_in, const int* in_sizes, int n_in,
                              void* d_out, int out_size, void* d_ws, size_t ws_size,
                              hipStream_t stream) {
    const float* x   = (const float*)d_in[0];
    const int* eidx  = (const int*)d_in[1];
    const int* batch = (const int*)d_in[2];
    const float* W1  = (const float*)d_in[3];
    const float* b1  = (const float*)d_in[4];
    const float* W2  = (const float*)d_in[5];
    const float* b2  = (const float*)d_in[6];
    const float* W3  = (const float*)d_in[7];
    const float* b3  = (const float*)d_in[8];
    const float* W4  = (const float*)d_in[9];
    const float* b4  = (const float*)d_in[10];

    const int* src = eidx;
    const int* dst = eidx + N_EDGES;

    float* out_xhat = (float*)d_out;
    float* out_z    = out_xhat + (size_t)N_NODES * 128;
    float* out_agg  = out_z + (size_t)N_NODES * 64;

    char* p = (char*)d_ws;
    auto alloc = [&](size_t bytes) { char* r = p; p += (bytes + 255) & ~(size_t)255; return r; };
    u16* arena0 = (u16*)alloc((size_t)N_NODES * 128 * 2);   // 12.8 MB
    u16* arena1 = (u16*)alloc((size_t)N_NODES * 128 * 2);   // 12.8 MB
    u16* c1     = (u16*)alloc((size_t)N_NODES * 64 * 2);    // 6.4 MB
    u16* c2     = (u16*)alloc((size_t)N_NODES * 64 * 2);    // 6.4 MB
    u16* wt1    = (u16*)alloc(128 * 128 * 2);
    u16* wt2    = (u16*)alloc(128 * 64 * 2);
    u16* wt3    = (u16*)alloc(64 * 128 * 2);
    u16* wt4    = (u16*)alloc(128 * 128 * 2);
    u32* bucket = (u32*)alloc((size_t)N_NODES * 128);       // 6.4 MB, 128B records
    u32* binCnt = (u32*)alloc(NBINS * 16 * 4);              // padded: 1 counter / 64B
    u32* binList= (u32*)alloc((size_t)NBINS * CAPB * 4);    // 4.0 MB
    float* dis  = (float*)alloc(N_NODES * 4);

    // preprocessing: two-pass LDS-binned bucket build; convert_wT fused as tail blocks
    hipMemsetAsync(binCnt, 0, NBINS * 16 * 4, stream);
    pre_scatter<<<NBLK_A + NCW, 256, 0, stream>>>(src, dst, binCnt, binList,
                                                  W1, wt1, W2, wt2, W3, wt3, W4, wt4);
    bucket_build<<<NBINS, 256, 0, stream>>>(binList, binCnt, bucket, dis);

    const int G128 = ((N_NODES + 63) / 64 * 2 + 3) / 4;  // 391
    const int TILES = (N_NODES + 63) / 64;               // 782

    // L1 GEMM: C1' = dis ⊙ (x W1)  [x read f32, in-reg cvt]
    gemm_mfma<128, 128, false, false, true, true><<<G128, 256, 0, stream>>>(
        x, wt1, nullptr, dis, arena1);
    // fused L1 prop + L2 GEMM: c1 = dis ⊙ (relu(di*(Σ+self)+b1) · W2)
    prop128_gemm64<<<PROP_BLOCKS, 256, 0, stream>>>(arena1, bucket, dis, b1, wt2, c1);
    // L2 prop: z = di*(Σ+self) + b2 → out_z (f32) + c2 = dis⊙z (bf16)
    propagate_k<64, false, true, true, true, true><<<PROP_BLOCKS, 256, 0, stream>>>(
        c1, bucket, dis, b2, out_z, c2);
    // L3 prop (c2 → c1) with pooling fused in last 512 blocks
    prop64_pool<<<PROP_BLOCKS, 256, 0, stream>>>(c2, bucket, dis, c1, out_z, batch, out_agg);
    // fused L3+L4 GEMMs: arena0 = dis ⊙ (relu(c1·W3 + b3) · W4)
    mlp2<<<TILES, 256, 0, stream>>>(c1, wt3, b3, wt4, dis, arena0);
    // L4 prop: x_hat = di*(Σ+self) + b4
    propagate_k<128, false, true, true, false, false><<<PROP_BLOCKS, 256, 0, stream>>>(
        arena0, bucket, dis, b4, out_xhat, nullptr);
}

// Round 17
// 225.290 us; speedup vs baseline: 1.3944x; 1.3944x over previous
//
#include <hip/hip_runtime.h>
#include <math.h>

#define N_NODES 50000
#define N_EDGES 800000
#define N_GRAPHS 512
#define CAP 62      // u16 slots per 128B bucket record; max degree (Poisson 16) ~45
#define NBINS 196   // bin = dst>>8 ; 196 bins of 256 nodes
#define CAPB 5120   // bin list capacity (expected ~4082, sigma ~64)
#define ABLK 4096   // edges per binning block (16/thread)
#define PROP_BLOCKS 2048
#define PROP_WAVES (PROP_BLOCKS * 4)
#define POOL_BLOCKS 512
#define P64_BLOCKS (PROP_BLOCKS - POOL_BLOCKS)  // 1536 prop blocks in fused kernel

typedef unsigned short u16;
typedef unsigned int u32;
typedef __attribute__((ext_vector_type(8))) short bf16x8_t;
typedef __attribute__((ext_vector_type(4))) float f32x4_t;
typedef __attribute__((ext_vector_type(4))) unsigned int u32x4_t;

constexpr int NBLK_A = (N_EDGES + ABLK - 1) / ABLK;  // 196
constexpr int WCONV_TOT = 49152;
constexpr int NCW = (WCONV_TOT + 255) / 256;         // 192

// ---- bf16 helpers (RTNE, finite values only) ----
__device__ __forceinline__ u16 f2bf(float f) {
    u32 u = __builtin_bit_cast(u32, f);
    return (u16)((u + 0x7fffu + ((u >> 16) & 1u)) >> 16);
}
__device__ __forceinline__ float bf2f(u16 s) {
    return __builtin_bit_cast(float, (u32)s << 16);
}
__device__ __forceinline__ float bf_lo(u32 u) { return __builtin_bit_cast(float, u << 16); }
__device__ __forceinline__ float bf_hi(u32 u) { return __builtin_bit_cast(float, u & 0xffff0000u); }

__device__ __forceinline__ bf16x8_t cvt8(const float* p) {
    float4 a = *reinterpret_cast<const float4*>(p);
    float4 b = *reinterpret_cast<const float4*>(p + 4);
    u32x4_t w;
    w.x = (u32)f2bf(a.x) | ((u32)f2bf(a.y) << 16);
    w.y = (u32)f2bf(a.z) | ((u32)f2bf(a.w) << 16);
    w.z = (u32)f2bf(b.x) | ((u32)f2bf(b.y) << 16);
    w.w = (u32)f2bf(b.z) | ((u32)f2bf(b.w) << 16);
    return __builtin_bit_cast(bf16x8_t, w);
}

// ---------------- block-wide exclusive scan helper (256 threads) ----------------
__device__ __forceinline__ int block_exscan(int val, int* lds, int tid) {
    lds[tid] = val;
    __syncthreads();
#pragma unroll
    for (int off = 1; off < 256; off <<= 1) {
        int t = (tid >= off) ? lds[tid - off] : 0;
        __syncthreads();
        lds[tid] += t;
        __syncthreads();
    }
    return lds[tid] - val;
}

// ---------------- pass 1: bin edges by dst>>8 (16 edges/thread) + convert_wT tail ----------
__global__ __launch_bounds__(256) void pre_scatter(const int* __restrict__ src,
                                                   const int* __restrict__ dst,
                                                   u32* __restrict__ binCnt,
                                                   u32* __restrict__ binList,
                                                   const float* __restrict__ W1, u16* __restrict__ wt1,
                                                   const float* __restrict__ W2, u16* __restrict__ wt2,
                                                   const float* __restrict__ W3, u16* __restrict__ wt3,
                                                   const float* __restrict__ W4, u16* __restrict__ wt4) {
    __shared__ int cur[256];
    __shared__ int lsStart[256];
    __shared__ int gbase[256];
    __shared__ int scanbuf[256];
    __shared__ u32 stage[ABLK];
    __shared__ int gpos[ABLK];
    int t = threadIdx.x;
    if (blockIdx.x >= NBLK_A) {
        int idx = (blockIdx.x - NBLK_A) * 256 + t;
        if (idx < WCONV_TOT) {
            const float* Wf;
            u16* Wt;
            int K, N, off;
            if (idx < 16384)      { Wf = W1; Wt = wt1; K = 128; N = 128; off = 0; }
            else if (idx < 24576) { Wf = W2; Wt = wt2; K = 128; N = 64;  off = 16384; }
            else if (idx < 32768) { Wf = W3; Wt = wt3; K = 64;  N = 128; off = 24576; }
            else                  { Wf = W4; Wt = wt4; K = 128; N = 128; off = 32768; }
            int q = idx - off;
            int k = q / N, n = q % N;
            Wt[n * K + k] = f2bf(Wf[q]);
        }
        return;
    }
    int e0 = blockIdx.x * ABLK;
    int nEdge = min(ABLK, N_EDGES - e0);  // 4096, or 1280 in last block (multiple of 4)

    cur[t] = 0;
    __syncthreads();

    int myBin[16], myRank[16];
    u32 myPack[16];
#pragma unroll
    for (int p = 0; p < 4; p++) {
        int off = p * 1024 + t * 4;
        bool ok = off < nEdge;
        int4 dv = ok ? *reinterpret_cast<const int4*>(dst + e0 + off) : make_int4(0, 0, 0, 0);
        int4 sv = ok ? *reinterpret_cast<const int4*>(src + e0 + off) : make_int4(0, 0, 0, 0);
        int ds[4] = {dv.x, dv.y, dv.z, dv.w};
        int ss[4] = {sv.x, sv.y, sv.z, sv.w};
#pragma unroll
        for (int j = 0; j < 4; j++) {
            int q = p * 4 + j;
            myBin[q] = ok ? (ds[j] >> 8) : -1;
            myPack[q] = (u32)(ss[j] & 0xFFFF) | ((u32)(ds[j] & 0xFF) << 16);
            myRank[q] = ok ? atomicAdd(&cur[ds[j] >> 8], 1) : 0;
        }
    }
    __syncthreads();
    int v = cur[t];
    int ex = block_exscan(v, scanbuf, t);
    lsStart[t] = ex;
    gbase[t] = (v > 0) ? (int)atomicAdd(&binCnt[t * 16], (u32)v) : 0;
    __syncthreads();
#pragma unroll
    for (int q = 0; q < 16; q++) {
        if (myBin[q] >= 0) {
            int idx = lsStart[myBin[q]] + myRank[q];
            int pq = gbase[myBin[q]] + myRank[q];
            stage[idx] = myPack[q];
            gpos[idx] = (pq < CAPB) ? (myBin[q] * CAPB + pq) : -1;
        }
    }
    __syncthreads();
    for (int i = t; i < nEdge; i += 256) {
        int pq = gpos[i];
        if (pq >= 0) binList[pq] = stage[i];
    }
}

// ---------------- pass 2: build 256-node bucket slice in LDS (stride-33 padded) -------
__global__ __launch_bounds__(256) void bucket_build(const u32* __restrict__ binList,
                                                    const u32* __restrict__ binCnt,
                                                    u32* __restrict__ bucket,
                                                    float* __restrict__ dis) {
    __shared__ u32 rec[256 * 33];  // 33.8 KB
    int b = blockIdx.x, t = threadIdx.x;
    for (int i = t; i < 256 * 33; i += 256) rec[i] = 0;
    __syncthreads();
    int ecnt = min((int)binCnt[b * 16], CAPB);
    const u32* lst = binList + (size_t)b * CAPB;
    u16* rec16 = reinterpret_cast<u16*>(rec);
    for (int i = t; i < ecnt; i += 256) {
        u32 pk = lst[i];
        int dlow = (pk >> 16) & 0xFF;
        int pos = (int)atomicAdd(&rec[dlow * 33], 1u);
        if (pos < CAP) rec16[dlow * 66 + 2 + pos] = (u16)(pk & 0xFFFF);
    }
    __syncthreads();
    int node0 = b * 256;
    int nNode = min(256, N_NODES - node0);
    for (int i = t; i < nNode * 32; i += 256)
        bucket[(size_t)node0 * 32 + i] = rec[(i >> 5) * 33 + (i & 31)];
    if (t < nNode) dis[node0 + t] = 1.0f / sqrtf((float)rec[t * 33] + 1.0f);
}

// ---------------- bf16 MFMA GEMM: C[M,N] = A[M,K] @ Wt[N,K]^T (+bias, relu, row-scale) --------
template <int N, int K, bool BIAS, bool RELU, bool SCALE, bool AF32>
__global__ __launch_bounds__(256) void gemm_mfma(const void* __restrict__ Avp,
                                                 const u16* __restrict__ Wt,
                                                 const float* __restrict__ bias,
                                                 const float* __restrict__ dis,
                                                 u16* __restrict__ C) {
    constexpr int KB = K / 32;
    constexpr int TN = N / 64;
    constexpr int TM = (N_NODES + 63) / 64;  // 782
    int wave = threadIdx.x >> 6;
    int lane = threadIdx.x & 63;
    int W = blockIdx.x * 4 + wave;
    if (W >= TM * TN) return;
    int tm = W / TN, tn = W % TN;
    int r16 = lane & 15;
    int kg = lane >> 4;

    bf16x8_t bf[4][KB];
#pragma unroll
    for (int nr = 0; nr < 4; nr++) {
        int colg = tn * 64 + nr * 16 + r16;
#pragma unroll
        for (int kb = 0; kb < KB; kb++)
            bf[nr][kb] = *reinterpret_cast<const bf16x8_t*>(Wt + (size_t)colg * K + kb * 32 + kg * 8);
    }

    f32x4_t acc[4][4];
#pragma unroll
    for (int mr = 0; mr < 4; mr++)
#pragma unroll
        for (int nr = 0; nr < 4; nr++)
#pragma unroll
            for (int t = 0; t < 4; t++) acc[mr][nr][t] = 0.f;

#pragma unroll
    for (int mr = 0; mr < 4; mr++) {
        int row = tm * 64 + mr * 16 + r16;
        if (row >= N_NODES) row = N_NODES - 1;
        bf16x8_t af[KB];
#pragma unroll
        for (int kb = 0; kb < KB; kb++) {
            if constexpr (AF32) {
                af[kb] = cvt8((const float*)Avp + (size_t)row * K + kb * 32 + kg * 8);
            } else {
                af[kb] = *reinterpret_cast<const bf16x8_t*>((const u16*)Avp + (size_t)row * K + kb * 32 + kg * 8);
            }
        }
#pragma unroll
        for (int kb = 0; kb < KB; kb++)
#pragma unroll
            for (int nr = 0; nr < 4; nr++)
                acc[mr][nr] = __builtin_amdgcn_mfma_f32_16x16x32_bf16(af[kb], bf[nr][kb],
                                                                      acc[mr][nr], 0, 0, 0);
    }

#pragma unroll
    for (int mr = 0; mr < 4; mr++) {
        float sc[4];
#pragma unroll
        for (int r = 0; r < 4; r++) {
            int row = tm * 64 + mr * 16 + kg * 4 + r;
            sc[r] = (SCALE && row < N_NODES) ? dis[row] : 1.f;
        }
#pragma unroll
        for (int nr = 0; nr < 4; nr++) {
            int colg = tn * 64 + nr * 16 + r16;
            float bv = BIAS ? bias[colg] : 0.f;
#pragma unroll
            for (int r = 0; r < 4; r++) {
                int row = tm * 64 + mr * 16 + kg * 4 + r;
                if (row < N_NODES) {
                    float v = acc[mr][nr][r] + bv;
                    if (RELU) v = fmaxf(v, 0.f);
                    if (SCALE) v *= sc[r];
                    C[(size_t)row * N + colg] = f2bf(v);
                }
            }
        }
    }
}

// ---------------- fused 2-layer MLP: out = dis ⊙ (relu(t·W3 + b3) · W4) ----------------
__global__ __launch_bounds__(256) void mlp2(const u16* __restrict__ t_in,   // [N_NODES][64]
                                            const u16* __restrict__ wt3,    // [128][64]
                                            const float* __restrict__ b3,
                                            const u16* __restrict__ wt4,    // [128][128]
                                            const float* __restrict__ dis,
                                            u16* __restrict__ out) {        // [N_NODES][128]
    __shared__ u16 h2s[64 * 128];  // 16 KB; byte addr swizzle: off ^= (row&7)<<4
    char* h2b = reinterpret_cast<char*>(h2s);
    int wv = threadIdx.x >> 6;
    int lane = threadIdx.x & 63;
    int r16 = lane & 15;
    int kg = lane >> 4;
    int row0 = blockIdx.x * 64;

    // ---- phase A: h2 cols [wv*32, wv*32+32) = relu(t_tile x W3 + b3) ----
    {
        bf16x8_t bf[2][2];
#pragma unroll
        for (int nr = 0; nr < 2; nr++) {
            int colg = wv * 32 + nr * 16 + r16;
#pragma unroll
            for (int kb = 0; kb < 2; kb++)
                bf[nr][kb] = *reinterpret_cast<const bf16x8_t*>(wt3 + (size_t)colg * 64 + kb * 32 + kg * 8);
        }
        f32x4_t acc[4][2];
#pragma unroll
        for (int mr = 0; mr < 4; mr++)
#pragma unroll
            for (int nr = 0; nr < 2; nr++)
#pragma unroll
                for (int q = 0; q < 4; q++) acc[mr][nr][q] = 0.f;
#pragma unroll
        for (int mr = 0; mr < 4; mr++) {
            int row = row0 + mr * 16 + r16;
            if (row >= N_NODES) row = N_NODES - 1;
            bf16x8_t af[2];
#pragma unroll
            for (int kb = 0; kb < 2; kb++)
                af[kb] = *reinterpret_cast<const bf16x8_t*>(t_in + (size_t)row * 64 + kb * 32 + kg * 8);
#pragma unroll
            for (int kb = 0; kb < 2; kb++)
#pragma unroll
                for (int nr = 0; nr < 2; nr++)
                    acc[mr][nr] = __builtin_amdgcn_mfma_f32_16x16x32_bf16(af[kb], bf[nr][kb],
                                                                          acc[mr][nr], 0, 0, 0);
        }
#pragma unroll
        for (int mr = 0; mr < 4; mr++) {
#pragma unroll
            for (int nr = 0; nr < 2; nr++) {
                int colg = wv * 32 + nr * 16 + r16;
                float bv = b3[colg];
#pragma unroll
                for (int r = 0; r < 4; r++) {
                    int rowl = mr * 16 + kg * 4 + r;
                    float v = fmaxf(acc[mr][nr][r] + bv, 0.f);
                    int off = rowl * 256 + colg * 2;
                    *reinterpret_cast<u16*>(h2b + (off ^ ((rowl & 7) << 4))) = f2bf(v);
                }
            }
        }
    }
    __syncthreads();

    // ---- phase B: out cols [wv*32, wv*32+32) = dis ⊙ (h2 x W4) ----
    {
        bf16x8_t bf[2][4];
#pragma unroll
        for (int nr = 0; nr < 2; nr++) {
            int colg = wv * 32 + nr * 16 + r16;
#pragma unroll
            for (int kb = 0; kb < 4; kb++)
                bf[nr][kb] = *reinterpret_cast<const bf16x8_t*>(wt4 + (size_t)colg * 128 + kb * 32 + kg * 8);
        }
        f32x4_t acc[4][2];
#pragma unroll
        for (int mr = 0; mr < 4; mr++)
#pragma unroll
            for (int nr = 0; nr < 2; nr++)
#pragma unroll
                for (int q = 0; q < 4; q++) acc[mr][nr][q] = 0.f;
#pragma unroll
        for (int mr = 0; mr < 4; mr++) {
            int rowl = mr * 16 + r16;
            bf16x8_t af[4];
#pragma unroll
            for (int kb = 0; kb < 4; kb++) {
                int off = rowl * 256 + kb * 64 + kg * 16;
                af[kb] = *reinterpret_cast<const bf16x8_t*>(h2b + (off ^ ((rowl & 7) << 4)));
            }
#pragma unroll
            for (int kb = 0; kb < 4; kb++)
#pragma unroll
                for (int nr = 0; nr < 2; nr++)
                    acc[mr][nr] = __builtin_amdgcn_mfma_f32_16x16x32_bf16(af[kb], bf[nr][kb],
                                                                          acc[mr][nr], 0, 0, 0);
        }
#pragma unroll
        for (int mr = 0; mr < 4; mr++) {
            float sc[4];
#pragma unroll
            for (int r = 0; r < 4; r++) {
                int row = row0 + mr * 16 + kg * 4 + r;
                sc[r] = (row < N_NODES) ? dis[row] : 1.f;
            }
#pragma unroll
            for (int nr = 0; nr < 2; nr++) {
                int colg = wv * 32 + nr * 16 + r16;
#pragma unroll
                for (int r = 0; r < 4; r++) {
                    int row = row0 + mr * 16 + kg * 4 + r;
                    if (row < N_NODES)
                        out[(size_t)row * 128 + colg] = f2bf(acc[mr][nr][r] * sc[r]);
                }
            }
        }
    }
}

// ---------------- propagate body over pre-scaled rows h' = dis ⊙ h ----------------
template <int F, bool RELU, bool BIAS, bool WF32, bool WBF16, bool SCALEOUT>
__device__ void prop_dev(const u16* __restrict__ h, const u32* __restrict__ bucket,
                         const float* __restrict__ dis, const float* __restrict__ bias,
                         float* __restrict__ out_f, u16* __restrict__ out_b,
                         int wid, int nwaves, int lane) {
    float2 bv2 = make_float2(0.f, 0.f);
    float bv1 = 0.f;
    if (BIAS) {
        if (F == 128) bv2 = reinterpret_cast<const float2*>(bias)[lane];
        else          bv1 = bias[lane];
    }
    for (int w = wid; w < N_NODES; w += nwaves) {
        const u32* bw = bucket + (size_t)w * 32;
        int deg = __builtin_amdgcn_readfirstlane(min((int)bw[0], CAP));
        const u16* slots = reinterpret_cast<const u16*>(bw) + 2;
        const u32* sw = reinterpret_cast<const u32*>(reinterpret_cast<const char*>(bw) + 4);
        float di = dis[w];

        if (F == 128) {
            const u32* hw = reinterpret_cast<const u32*>(h);  // 64 u32 per row
            float2 a0 = {0.f, 0.f}, a1 = {0.f, 0.f}, a2 = {0.f, 0.f}, a3 = {0.f, 0.f};
            int i = 0;
            for (; i + 16 <= deg; i += 16) {
                u32 cw[8], hv[16];
#pragma unroll
                for (int j = 0; j < 8; j++) cw[j] = sw[(i >> 1) + j];
#pragma unroll
                for (int j = 0; j < 8; j++) {
                    hv[2 * j]     = hw[(size_t)(cw[j] & 0xffffu) * 64 + lane];
                    hv[2 * j + 1] = hw[(size_t)(cw[j] >> 16) * 64 + lane];
                }
#pragma unroll
                for (int j = 0; j < 16; j++) {
                    float lo = bf_lo(hv[j]), hi = bf_hi(hv[j]);
                    if ((j & 3) == 0) { a0.x += lo; a0.y += hi; }
                    else if ((j & 3) == 1) { a1.x += lo; a1.y += hi; }
                    else if ((j & 3) == 2) { a2.x += lo; a2.y += hi; }
                    else { a3.x += lo; a3.y += hi; }
                }
            }
            for (; i + 8 <= deg; i += 8) {
                u32 cw[4], hv[8];
#pragma unroll
                for (int j = 0; j < 4; j++) cw[j] = sw[(i >> 1) + j];
#pragma unroll
                for (int j = 0; j < 4; j++) {
                    hv[2 * j]     = hw[(size_t)(cw[j] & 0xffffu) * 64 + lane];
                    hv[2 * j + 1] = hw[(size_t)(cw[j] >> 16) * 64 + lane];
                }
#pragma unroll
                for (int j = 0; j < 8; j++) {
                    float lo = bf_lo(hv[j]), hi = bf_hi(hv[j]);
                    if ((j & 3) == 0) { a0.x += lo; a0.y += hi; }
                    else if ((j & 3) == 1) { a1.x += lo; a1.y += hi; }
                    else if ((j & 3) == 2) { a2.x += lo; a2.y += hi; }
                    else { a3.x += lo; a3.y += hi; }
                }
            }
            for (; i < deg; i++) {
                u32 u = hw[(size_t)slots[i] * 64 + lane];
                a0.x += bf_lo(u);
                a0.y += bf_hi(u);
            }
            u32 su = hw[(size_t)w * 64 + lane];
            float ox = (a0.x + a1.x + a2.x + a3.x + bf_lo(su)) * di;
            float oy = (a0.y + a1.y + a2.y + a3.y + bf_hi(su)) * di;
            if (BIAS) { ox += bv2.x; oy += bv2.y; }
            if (RELU) { ox = fmaxf(ox, 0.f); oy = fmaxf(oy, 0.f); }
            if (WF32) {
                reinterpret_cast<float2*>(out_f + (size_t)w * 128)[lane] = make_float2(ox, oy);
            }
            if (WBF16) {
                float wx = SCALEOUT ? ox * di : ox;
                float wy = SCALEOUT ? oy * di : oy;
                u32 pk = (u32)f2bf(wx) | ((u32)f2bf(wy) << 16);
                reinterpret_cast<u32*>(out_b)[(size_t)w * 64 + lane] = pk;
            }
        } else {
            float a0 = 0.f, a1 = 0.f, a2 = 0.f, a3 = 0.f;
            int i = 0;
            for (; i + 16 <= deg; i += 16) {
                u32 cw[8];
                u16 hv[16];
#pragma unroll
                for (int j = 0; j < 8; j++) cw[j] = sw[(i >> 1) + j];
#pragma unroll
                for (int j = 0; j < 8; j++) {
                    hv[2 * j]     = h[(size_t)(cw[j] & 0xffffu) * 64 + lane];
                    hv[2 * j + 1] = h[(size_t)(cw[j] >> 16) * 64 + lane];
                }
#pragma unroll
                for (int j = 0; j < 16; j++) {
                    float v = bf2f(hv[j]);
                    if ((j & 3) == 0) a0 += v;
                    else if ((j & 3) == 1) a1 += v;
                    else if ((j & 3) == 2) a2 += v;
                    else a3 += v;
                }
            }
            for (; i + 8 <= deg; i += 8) {
                u32 cw[4];
                u16 hv[8];
#pragma unroll
                for (int j = 0; j < 4; j++) cw[j] = sw[(i >> 1) + j];
#pragma unroll
                for (int j = 0; j < 4; j++) {
                    hv[2 * j]     = h[(size_t)(cw[j] & 0xffffu) * 64 + lane];
                    hv[2 * j + 1] = h[(size_t)(cw[j] >> 16) * 64 + lane];
                }
#pragma unroll
                for (int j = 0; j < 8; j++) {
                    float v = bf2f(hv[j]);
                    if ((j & 3) == 0) a0 += v;
                    else if ((j & 3) == 1) a1 += v;
                    else if ((j & 3) == 2) a2 += v;
                    else a3 += v;
                }
            }
            for (; i < deg; i++) a0 += bf2f(h[(size_t)slots[i] * 64 + lane]);
            float o = (a0 + a1 + a2 + a3 + bf2f(h[(size_t)w * 64 + lane])) * di;
            if (BIAS) o += bv1;
            if (RELU) o = fmaxf(o, 0.f);
            if (WF32) out_f[(size_t)w * 64 + lane] = o;
            if (WBF16) out_b[(size_t)w * 64 + lane] = f2bf(SCALEOUT ? o * di : o);
        }
    }
}

template <int F, bool RELU, bool BIAS, bool WF32, bool WBF16, bool SCALEOUT>
__global__ __launch_bounds__(256) void propagate_k(const u16* __restrict__ h,
                                                   const u32* __restrict__ bucket,
                                                   const float* __restrict__ dis,
                                                   const float* __restrict__ bias,
                                                   float* __restrict__ out_f,
                                                   u16* __restrict__ out_b) {
    prop_dev<F, RELU, BIAS, WF32, WBF16, SCALEOUT>(h, bucket, dis, bias, out_f, out_b,
        (int)(blockIdx.x * 4 + (threadIdx.x >> 6)), PROP_WAVES, threadIdx.x & 63);
}

// ---------------- L3 propagate + pooling fused (role split by blockIdx) ----------------
__global__ __launch_bounds__(256) void prop64_pool(const u16* __restrict__ h,
                                                   const u32* __restrict__ bucket,
                                                   const float* __restrict__ dis,
                                                   u16* __restrict__ out_b,
                                                   const float* __restrict__ z,
                                                   const int* __restrict__ batch,
                                                   float* __restrict__ agg) {
    int wave = threadIdx.x >> 6;
    int lane = threadIdx.x & 63;
    if (blockIdx.x >= P64_BLOCKS) {
        __shared__ float part[3][64];
        int g = blockIdx.x - P64_BLOCKS;  // one graph per block
        int l = 0, hh = N_NODES;
        while (l < hh) { int m = (l + hh) >> 1; if (batch[m] < g) l = m + 1; else hh = m; }
        int s = l;
        hh = N_NODES;
        while (l < hh) { int m = (l + hh) >> 1; if (batch[m] < g + 1) l = m + 1; else hh = m; }
        int e = l;
        float acc[4] = {0.f, 0.f, 0.f, 0.f};
        int i = s + wave;
        for (; i + 28 < e; i += 32) {  // 8 independent loads in flight
            float v[8];
#pragma unroll
            for (int j = 0; j < 8; j++) v[j] = z[(size_t)(i + j * 4) * 64 + lane];
#pragma unroll
            for (int j = 0; j < 8; j++) acc[j & 3] += v[j];
        }
        for (; i < e; i += 4) acc[0] += z[(size_t)i * 64 + lane];
        float a = acc[0] + acc[1] + acc[2] + acc[3];
        if (wave) part[wave - 1][lane] = a;
        __syncthreads();
        if (wave == 0) {
            a += part[0][lane] + part[1][lane] + part[2][lane];
            agg[(size_t)g * 64 + lane] = a / fmaxf((float)(e - s), 1.0f);
        }
        return;
    }
    prop_dev<64, false, false, false, true, false>(h, bucket, dis, nullptr, nullptr, out_b,
        (int)(blockIdx.x * 4 + wave), P64_BLOCKS * 4, lane);
}

extern "C" void kernel_launch(void* const* d_in, const int* in_sizes, int n_in,
                              void* d_out, int out_size, void* d_ws, size_t ws_size,
                              hipStream_t stream) {
    const float* x   = (const float*)d_in[0];
    const int* eidx  = (const int*)d_in[1];
    const int* batch = (const int*)d_in[2];
    const float* W1  = (const float*)d_in[3];
    const float* b1  = (const float*)d_in[4];
    const float* W2  = (const float*)d_in[5];
    const float* b2  = (const float*)d_in[6];
    const float* W3  = (const float*)d_in[7];
    const float* b3  = (const float*)d_in[8];
    const float* W4  = (const float*)d_in[9];
    const float* b4  = (const float*)d_in[10];

    const int* src = eidx;
    const int* dst = eidx + N_EDGES;

    float* out_xhat = (float*)d_out;
    float* out_z    = out_xhat + (size_t)N_NODES * 128;
    float* out_agg  = out_z + (size_t)N_NODES * 64;

    char* p = (char*)d_ws;
    auto alloc = [&](size_t bytes) { char* r = p; p += (bytes + 255) & ~(size_t)255; return r; };
    u16* arena0 = (u16*)alloc((size_t)N_NODES * 128 * 2);   // 12.8 MB
    u16* arena1 = (u16*)alloc((size_t)N_NODES * 128 * 2);   // 12.8 MB
    u16* c1     = (u16*)alloc((size_t)N_NODES * 64 * 2);    // 6.4 MB
    u16* c2     = (u16*)alloc((size_t)N_NODES * 64 * 2);    // 6.4 MB
    u16* wt1    = (u16*)alloc(128 * 128 * 2);
    u16* wt2    = (u16*)alloc(128 * 64 * 2);
    u16* wt3    = (u16*)alloc(64 * 128 * 2);
    u16* wt4    = (u16*)alloc(128 * 128 * 2);
    u32* bucket = (u32*)alloc((size_t)N_NODES * 128);       // 6.4 MB, 128B records
    u32* binCnt = (u32*)alloc(NBINS * 16 * 4);              // padded: 1 counter / 64B
    u32* binList= (u32*)alloc((size_t)NBINS * CAPB * 4);    // 4.0 MB
    float* dis  = (float*)alloc(N_NODES * 4);

    // preprocessing: two-pass LDS-binned bucket build; convert_wT fused as tail blocks
    hipMemsetAsync(binCnt, 0, NBINS * 16 * 4, stream);
    pre_scatter<<<NBLK_A + NCW, 256, 0, stream>>>(src, dst, binCnt, binList,
                                                  W1, wt1, W2, wt2, W3, wt3, W4, wt4);
    bucket_build<<<NBINS, 256, 0, stream>>>(binList, binCnt, bucket, dis);

    const int G128 = ((N_NODES + 63) / 64 * 2 + 3) / 4;  // 391
    const int G64  = ((N_NODES + 63) / 64 * 1 + 3) / 4;  // 196
    const int TILES = (N_NODES + 63) / 64;               // 782

    // L1: C1' = dis ⊙ (x W1) [x read f32, in-reg cvt]; h1 = relu(di*(Σ+self) + b1)
    gemm_mfma<128, 128, false, false, true, true><<<G128, 256, 0, stream>>>(
        x, wt1, nullptr, dis, arena1);
    propagate_k<128, true, true, false, true, false><<<PROP_BLOCKS, 256, 0, stream>>>(
        arena1, bucket, dis, b1, nullptr, arena0);
    // L2: C2' = dis ⊙ (h1 W2); z = di*(Σ+self) + b2 → out_z (f32) + c2 = dis⊙z (bf16)
    gemm_mfma<64, 128, false, false, true, false><<<G64, 256, 0, stream>>>(
        arena0, wt2, nullptr, dis, c1);
    propagate_k<64, false, true, true, true, true><<<PROP_BLOCKS, 256, 0, stream>>>(
        c1, bucket, dis, b2, out_z, c2);
    // L3 prop (c2 → c1) with pooling fused in last 512 blocks
    prop64_pool<<<PROP_BLOCKS, 256, 0, stream>>>(c2, bucket, dis, c1, out_z, batch, out_agg);
    // fused L3+L4 GEMMs: arena0 = dis ⊙ (relu(c1·W3 + b3) · W4)   [h2 via swizzled LDS]
    mlp2<<<TILES, 256, 0, stream>>>(c1, wt3, b3, wt4, dis, arena0);
    // L4 prop: x_hat = di*(Σ+self) + b4
    propagate_k<128, false, true, true, false, false><<<PROP_BLOCKS, 256, 0, stream>>>(
        arena0, bucket, dis, b4, out_xhat, nullptr);
}